// Round 10
// baseline (430.804 us; speedup 1.0000x reference)
//
#include <hip/hip_runtime.h>
#include <hip/hip_cooperative_groups.h>

namespace cg = cooperative_groups;

#define NB 4
#define C 64
#define H 256
#define W 256
#define HW (H * W)
#define NH 10
#define KK 5
#define NBINS 1024
#define CHUNK 256
#define NCHUNK (HW / CHUNK)
#define MAXGRID 2048

// ================= device phase functions (shared by both paths) =================

// ---- sumsq unit: u in [0, 2048), layout part1[b*512 + ch] ----
__device__ __forceinline__ void sumsq_unit(int u, int t, float* smA,
                                           const float* __restrict__ x,
                                           float* __restrict__ part1) {
    int b = u >> 9, ch = u & 511;
    const float4* p = reinterpret_cast<const float4*>(x + (size_t)b * C * HW) + (size_t)ch * 2048;
    float s = 0.f;
    for (int i = t; i < 2048; i += 256) {
        float4 v = p[i];
        s += v.x * v.x + v.y * v.y + v.z * v.z + v.w * v.w;
    }
    smA[t] = s;
    __syncthreads();
    for (int off = 128; off; off >>= 1) {
        if (t < off) smA[t] += smA[t + off];
        __syncthreads();
    }
    if (t == 0) part1[u] = smA[0];
    __syncthreads();
}

// ---- redundant per-block argmax over part[NB][per_batch] (uses smA as 256 float4) ----
__device__ __forceinline__ int block_argmax(int t, float* smA,
                                            const float* __restrict__ part, int per_batch) {
    float4* red4 = reinterpret_cast<float4*>(smA);
    float4 ss = make_float4(0.f, 0.f, 0.f, 0.f);
    int q4 = per_batch >> 2;
    for (int i = t; i < q4; i += 256) {
        float4 a = *reinterpret_cast<const float4*>(part + 0 * per_batch + i * 4);
        float4 b = *reinterpret_cast<const float4*>(part + 1 * per_batch + i * 4);
        float4 c = *reinterpret_cast<const float4*>(part + 2 * per_batch + i * 4);
        float4 d = *reinterpret_cast<const float4*>(part + 3 * per_batch + i * 4);
        ss.x += a.x + a.y + a.z + a.w;
        ss.y += b.x + b.y + b.z + b.w;
        ss.z += c.x + c.y + c.z + c.w;
        ss.w += d.x + d.y + d.z + d.w;
    }
    red4[t] = ss;
    __syncthreads();
    for (int off = 128; off; off >>= 1) {
        if (t < off) {
            red4[t].x += red4[t + off].x;
            red4[t].y += red4[t + off].y;
            red4[t].z += red4[t + off].z;
            red4[t].w += red4[t + off].w;
        }
        __syncthreads();
    }
    float4 nm = red4[0];
    __syncthreads();
    float nv[NB] = {nm.x, nm.y, nm.z, nm.w};
    int best = 0;
    float m = nv[0];
#pragma unroll
    for (int i = 1; i < NB; i++)
        if (nv[i] > m) { m = nv[i]; best = i; }
    return best;
}

// ---- hash: LSH + conv projections of best plane, 8-channel LDS strips ----
__device__ __forceinline__ void hash_phase(int u, int t, float* smA, float* smB,
        const float* __restrict__ Xall, const float* __restrict__ part, int per_batch,
        const float* __restrict__ rvecs, const float* __restrict__ cwg,
        float* __restrict__ filtU, int* __restrict__ dec, int* __restrict__ hist) {
    float* rv = smB;
    float* cw = smB + NH * C;
    int* lhist = reinterpret_cast<int*>(smB + 2 * NH * C);
    for (int i = t; i < NH * C; i += 256) { rv[i] = rvecs[i]; cw[i] = cwg[i]; }
    for (int i = t; i < NBINS; i += 256) lhist[i] = 0;
    int best = block_argmax(t, smA, part, per_batch);

    const float* X = Xall + (size_t)best * C * HW;
    int p0 = u * CHUNK;
    float acc[NH], cacc[NH];
#pragma unroll
    for (int h = 0; h < NH; h++) { acc[h] = 0.f; cacc[h] = 0.f; }
    float(*tile)[CHUNK + 4] = reinterpret_cast<float(*)[CHUNK + 4]>(smA);
    for (int s8 = 0; s8 < 8; s8++) {
        __syncthreads();
#pragma unroll
        for (int k = 0; k < 2; k++) {
            int idx = t + k * 256;
            int cl = idx >> 6;
            int lane = idx & 63;
            float4 v = *reinterpret_cast<const float4*>(
                X + (size_t)(s8 * 8 + cl) * HW + p0 + lane * 4);
            *reinterpret_cast<float4*>(&tile[cl][lane * 4]) = v;
        }
        __syncthreads();
#pragma unroll
        for (int c = 0; c < 8; c++) {
            float v = tile[c][t];
            int ci = s8 * 8 + c;
#pragma unroll
            for (int h = 0; h < NH; h++) {
                acc[h] += v * rv[h * C + ci];
                cacc[h] += v * cw[h * C + ci];
            }
        }
    }
    int d = 0;
#pragma unroll
    for (int h = 0; h < NH; h++) d |= (acc[h] > 0.f) ? (1 << h) : 0;
    dec[p0 + t] = d;
    atomicAdd(&lhist[d], 1);
    float sg[NH];
#pragma unroll
    for (int h = 0; h < NH; h++) sg[h] = 1.f / (1.f + expf(-cacc[h]));
    float* fu = filtU + (size_t)(p0 + t) * 12;
    *reinterpret_cast<float4*>(fu + 0) = make_float4(sg[0], sg[1], sg[2], sg[3]);
    *reinterpret_cast<float4*>(fu + 4) = make_float4(sg[4], sg[5], sg[6], sg[7]);
    *reinterpret_cast<float4*>(fu + 8) = make_float4(sg[8], sg[9], 0.f, 0.f);
    __syncthreads();
    for (int i = t; i < NBINS; i += 256) hist[(size_t)i * NCHUNK + u] = lhist[i];
    __syncthreads();
}

// ---- per-bin chunk scan: u in [0, NBINS/4), one bin per wave ----
__device__ __forceinline__ void scan_phase(int u, int t, int* __restrict__ hist,
                                           int* __restrict__ bintot) {
    int lane = t & 63;
    int b = u * 4 + (t >> 6);
    int4 v = *reinterpret_cast<int4*>(hist + (size_t)b * NCHUNK + lane * 4);
    int s0 = v.x, s1 = s0 + v.y, s2 = s1 + v.z, s3 = s2 + v.w;
    int s = s3;
#pragma unroll
    for (int off = 1; off < 64; off <<= 1) {
        int nbr = __shfl_up(s, off);
        if (lane >= off) s += nbr;
    }
    int excl = s - s3;
    int4 o;
    o.x = excl;
    o.y = excl + s0;
    o.z = excl + s1;
    o.w = excl + s2;
    *reinterpret_cast<int4*>(hist + (size_t)b * NCHUNK + lane * 4) = o;
    if (lane == 63) bintot[b] = s;
}

// ---- stable scatter: filt written directly at sorted position ----
__device__ __forceinline__ void scatter_phase(int u, int t, float* smA,
        const int* __restrict__ dec, const int* __restrict__ hist,
        const int* __restrict__ bintot, const float* __restrict__ filtU,
        float* __restrict__ filt) {
    int* boffs = reinterpret_cast<int*>(smA);
    int* wtot = boffs + NBINS;
    int* keys = wtot + 4;
    int lane = t & 63;
    int w = t >> 6;
    int4 v = *reinterpret_cast<const int4*>(bintot + t * 4);
    int s0 = v.x, s1 = s0 + v.y, s2 = s1 + v.z, s3 = s2 + v.w;
    int s = s3;
#pragma unroll
    for (int off = 1; off < 64; off <<= 1) {
        int nbr = __shfl_up(s, off);
        if (lane >= off) s += nbr;
    }
    int excl = s - s3;
    if (lane == 63) wtot[w] = s;
    __syncthreads();
    int wbase = 0;
#pragma unroll
    for (int i = 0; i < 4; i++) wbase += (i < w) ? wtot[i] : 0;
    boffs[t * 4 + 0] = wbase + excl;
    boffs[t * 4 + 1] = wbase + excl + s0;
    boffs[t * 4 + 2] = wbase + excl + s1;
    boffs[t * 4 + 3] = wbase + excl + s2;

    int p0 = u * CHUNK;
    int k = dec[p0 + t];
    keys[t] = k;
    __syncthreads();
    int r = 0;
    for (int j = 0; j < t; j++) r += (keys[j] == k) ? 1 : 0;
    int dst = boffs[k] + hist[(size_t)k * NCHUNK + u] + r;

    const float4* fu = reinterpret_cast<const float4*>(filtU + (size_t)(p0 + t) * 12);
    float4 a = fu[0], b4 = fu[1], c4 = fu[2];
    float vv[10] = {a.x, a.y, a.z, a.w, b4.x, b4.y, b4.z, b4.w, c4.x, c4.y};
#pragma unroll
    for (int h = 0; h < NH; h++) filt[(size_t)h * HW + dst] = vv[h];
    __syncthreads();
}

// ---- horizontal conv unit (4 rows) + part2 partial; u in [0, 4096) ----
__device__ __forceinline__ void convh_unit(int u, int t, float* smA,
        const float* __restrict__ X, const float* __restrict__ filt,
        float* __restrict__ out1, float* __restrict__ part2) {
    int rb = u & 63;
    int c = (u >> 6) & (C - 1);
    int n = u >> 12;
    int g = c >> 5;
    int x4 = (t & 63) * 4;
    int y = rb * 4 + (t >> 6);

    const float* src = X + (((size_t)n * C + c) * H + y) * W;
    float4 M = *reinterpret_cast<const float4*>(src + x4);
    float s0, s1, s6, s7;
    if (x4 > 0) {
        float4 L = *reinterpret_cast<const float4*>(src + x4 - 4);
        s0 = L.z; s1 = L.w;
    } else {
        s0 = M.z; s1 = M.y;
    }
    if (x4 < W - 4) {
        float4 R = *reinterpret_cast<const float4*>(src + x4 + 4);
        s6 = R.x; s7 = R.y;
    } else {
        s6 = M.z; s7 = M.y;
    }
    float s[8] = {s0, s1, M.x, M.y, M.z, M.w, s6, s7};

    const float* fb = filt + (size_t)g * KK * HW + (size_t)y * W + x4;
    float4 acc = make_float4(0.f, 0.f, 0.f, 0.f);
#pragma unroll
    for (int k = 0; k < KK; k++) {
        float4 f = *reinterpret_cast<const float4*>(fb + (size_t)k * HW);
        acc.x += s[k] * f.x;
        acc.y += s[k + 1] * f.y;
        acc.z += s[k + 2] * f.z;
        acc.w += s[k + 3] * f.w;
    }
    *reinterpret_cast<float4*>(out1 + (((size_t)n * C + c) * H + y) * W + x4) = acc;

    float ss = acc.x * acc.x + acc.y * acc.y + acc.z * acc.z + acc.w * acc.w;
#pragma unroll
    for (int off = 32; off; off >>= 1) ss += __shfl_down(ss, off);
    if ((t & 63) == 0) smA[t >> 6] = ss;
    __syncthreads();
    if (t == 0) part2[u] = smA[0] + smA[1] + smA[2] + smA[3];
    __syncthreads();
}

// ---- vertical conv unit (TY=16) + affine; u in [0, 1024) ----
__device__ __forceinline__ void convv_unit(int u, int t,
        const float* __restrict__ out1, const float* __restrict__ filt,
        const float* __restrict__ x, const float* __restrict__ gamma,
        const float* __restrict__ beta, float* __restrict__ out) {
    int yc = u & 3;
    int c = (u >> 2) & (C - 1);
    int n = u >> 8;
    int g = c >> 5;
    int x4 = (t & 63) * 4;
    int ys = yc * 64 + (t >> 6) * 16;

    const float* plane = out1 + ((size_t)n * C + c) * HW;
    float4 win[KK];
#pragma unroll
    for (int i = 0; i < 4; i++) {
        int yy = ys - 2 + i;
        yy = yy < 0 ? -yy : yy;
        win[i] = *reinterpret_cast<const float4*>(plane + (size_t)yy * W + x4);
    }
    float gm = gamma[c], bt = beta[c];
    const float* fgb = filt + (size_t)g * KK * HW;
    for (int dy = 0; dy < 16; dy++) {
        int y = ys + dy;
        int yy = y + 2;
        yy = (yy >= H) ? (2 * H - 2 - yy) : yy;
        win[4] = *reinterpret_cast<const float4*>(plane + (size_t)yy * W + x4);
        const float* fb = fgb + (size_t)y * W + x4;
        float4 acc = make_float4(0.f, 0.f, 0.f, 0.f);
#pragma unroll
        for (int k = 0; k < KK; k++) {
            float4 f = *reinterpret_cast<const float4*>(fb + (size_t)k * HW);
            acc.x += win[k].x * f.x;
            acc.y += win[k].y * f.y;
            acc.z += win[k].z * f.z;
            acc.w += win[k].w * f.w;
        }
        size_t idx = (((size_t)n * C + c) * H + y) * W + x4;
        float4 xv = *reinterpret_cast<const float4*>(x + idx);
        float4 o;
        o.x = gm * acc.x + bt * xv.x;
        o.y = gm * acc.y + bt * xv.y;
        o.z = gm * acc.z + bt * xv.z;
        o.w = gm * acc.w + bt * xv.w;
        *reinterpret_cast<float4*>(out + idx) = o;
#pragma unroll
        for (int k = 0; k < 4; k++) win[k] = win[k + 1];
    }
}

// ================= cooperative mega-kernel (grid-stride phases) =================
__global__ __launch_bounds__(256) void mega_kernel(
        const float* __restrict__ x, const float* __restrict__ convh_w,
        const float* __restrict__ convw_w, const float* __restrict__ rvh,
        const float* __restrict__ rvw, const float* __restrict__ gamma,
        const float* __restrict__ beta, float* __restrict__ out,
        float* __restrict__ out1, float* __restrict__ filtU, float* __restrict__ filt,
        int* __restrict__ dec, int* __restrict__ hist, int* __restrict__ bintot,
        float* __restrict__ part1, float* __restrict__ part2) {
    cg::grid_group grid = cg::this_grid();
    __shared__ __align__(16) float smA[2080];
    __shared__ __align__(16) float smB[2304];
    int t = threadIdx.x;
    int bid = blockIdx.x;
    int gd = gridDim.x;

    for (int u = bid; u < 2048; u += gd) sumsq_unit(u, t, smA, x, part1);
    grid.sync();
    for (int u = bid; u < NCHUNK; u += gd)
        hash_phase(u, t, smA, smB, x, part1, 512, rvh, convh_w, filtU, dec, hist);
    grid.sync();
    for (int u = bid; u < NBINS / 4; u += gd) scan_phase(u, t, hist, bintot);
    grid.sync();
    for (int u = bid; u < NCHUNK; u += gd)
        scatter_phase(u, t, smA, dec, hist, bintot, filtU, filt);
    grid.sync();
    for (int u = bid; u < NB * C * (H / 4); u += gd)
        convh_unit(u, t, smA, x, filt, out1, part2);
    grid.sync();
    for (int u = bid; u < NCHUNK; u += gd)
        hash_phase(u, t, smA, smB, out1, part2, 4096, rvw, convw_w, filtU, dec, hist);
    grid.sync();
    for (int u = bid; u < NBINS / 4; u += gd) scan_phase(u, t, hist, bintot);
    grid.sync();
    for (int u = bid; u < NCHUNK; u += gd)
        scatter_phase(u, t, smA, dec, hist, bintot, filtU, filt);
    grid.sync();
    for (int u = bid; u < NB * C * 4; u += gd)
        convv_unit(u, t, out1, filt, x, gamma, beta, out);
}

// ================= fallback wrappers (R8-equivalent chain) =================
__global__ __launch_bounds__(256) void k_sumsq(const float* __restrict__ x,
                                               float* __restrict__ part1) {
    __shared__ __align__(16) float smA[256];
    sumsq_unit(blockIdx.x, threadIdx.x, smA, x, part1);
}
__global__ __launch_bounds__(256) void k_hash(const float* __restrict__ Xall,
        const float* __restrict__ part, int per_batch, const float* __restrict__ rvecs,
        const float* __restrict__ cwg, float* __restrict__ filtU,
        int* __restrict__ dec, int* __restrict__ hist) {
    __shared__ __align__(16) float smA[2080];
    __shared__ __align__(16) float smB[2304];
    hash_phase(blockIdx.x, threadIdx.x, smA, smB, Xall, part, per_batch, rvecs, cwg,
               filtU, dec, hist);
}
__global__ __launch_bounds__(256) void k_scan(int* __restrict__ hist,
                                              int* __restrict__ bintot) {
    scan_phase(blockIdx.x, threadIdx.x, hist, bintot);
}
__global__ __launch_bounds__(256) void k_scatter(const int* __restrict__ dec,
        const int* __restrict__ hist, const int* __restrict__ bintot,
        const float* __restrict__ filtU, float* __restrict__ filt) {
    __shared__ __align__(16) float smA[1312];
    scatter_phase(blockIdx.x, threadIdx.x, smA, dec, hist, bintot, filtU, filt);
}
__global__ __launch_bounds__(256) void k_convh(const float* __restrict__ X,
        const float* __restrict__ filt, float* __restrict__ out1,
        float* __restrict__ part2) {
    __shared__ __align__(16) float smA[4];
    convh_unit(blockIdx.x, threadIdx.x, smA, X, filt, out1, part2);
}
__global__ __launch_bounds__(256) void k_convv(const float* __restrict__ out1,
        const float* __restrict__ filt, const float* __restrict__ x,
        const float* __restrict__ gamma, const float* __restrict__ beta,
        float* __restrict__ out) {
    convv_unit(blockIdx.x, threadIdx.x, out1, filt, x, gamma, beta, out);
}

extern "C" void kernel_launch(void* const* d_in, const int* in_sizes, int n_in,
                              void* d_out, int out_size, void* d_ws, size_t ws_size,
                              hipStream_t stream) {
    const float* x      = (const float*)d_in[0];
    const float* conv_h = (const float*)d_in[1];
    const float* conv_w = (const float*)d_in[2];
    const float* rv_h   = (const float*)d_in[3];
    const float* rv_w   = (const float*)d_in[4];
    const float* gamma  = (const float*)d_in[5];
    const float* beta   = (const float*)d_in[6];
    float* out = (float*)d_out;

    char* w = (char*)d_ws;
    size_t off = 0;
    float* out1   = (float*)(w + off); off += (size_t)NB * C * HW * 4;
    float* filtU  = (float*)(w + off); off += (size_t)HW * 12 * 4;
    float* filt   = (float*)(w + off); off += (size_t)NH * HW * 4;
    int*   dec    = (int*)  (w + off); off += (size_t)HW * 4;
    int*   hist   = (int*)  (w + off); off += (size_t)NBINS * NCHUNK * 4;
    int*   bintot = (int*)  (w + off); off += 4096;
    float* part1  = (float*)(w + off); off += (size_t)NB * 512 * 4;
    float* part2  = (float*)(w + off); off += (size_t)NB * 4096 * 4;

    // deterministic host-side occupancy query (no stream ops, graph-safe)
    int dev = 0;
    (void)hipGetDevice(&dev);
    int nMP = 0;
    (void)hipDeviceGetAttribute(&nMP, hipDeviceAttributeMultiprocessorCount, dev);
    int bpm = 0;
    hipError_t oe = hipOccupancyMaxActiveBlocksPerMultiprocessor(&bpm, mega_kernel, 256, 0);

    bool coop_ok = false;
    if (oe == hipSuccess && nMP > 0 && bpm > 0) {
        int G = nMP * bpm;
        if (G > MAXGRID) G = MAXGRID;
        if (G >= 64) {
            void* args[] = {&x, &conv_h, &conv_w, &rv_h, &rv_w, &gamma, &beta,
                            &out, &out1, &filtU, &filt, &dec, &hist, &bintot,
                            &part1, &part2};
            hipError_t le = hipLaunchCooperativeKernel(
                reinterpret_cast<void*>(mega_kernel), dim3(G), dim3(256), args, 0, stream);
            coop_ok = (le == hipSuccess);
        }
    }

    if (!coop_ok) {
        // proven R8-style chain
        k_sumsq<<<2048, 256, 0, stream>>>(x, part1);
        k_hash<<<NCHUNK, 256, 0, stream>>>(x, part1, 512, rv_h, conv_h, filtU, dec, hist);
        k_scan<<<NBINS / 4, 256, 0, stream>>>(hist, bintot);
        k_scatter<<<NCHUNK, 256, 0, stream>>>(dec, hist, bintot, filtU, filt);
        k_convh<<<NB * C * (H / 4), 256, 0, stream>>>(x, filt, out1, part2);
        k_hash<<<NCHUNK, 256, 0, stream>>>(out1, part2, 4096, rv_w, conv_w, filtU, dec, hist);
        k_scan<<<NBINS / 4, 256, 0, stream>>>(hist, bintot);
        k_scatter<<<NCHUNK, 256, 0, stream>>>(dec, hist, bintot, filtU, filt);
        k_convv<<<NB * C * 4, 256, 0, stream>>>(out1, filt, x, gamma, beta, out);
    }
}

// Round 11
// 139.275 us; speedup vs baseline: 3.0932x; 3.0932x over previous
//
#include <hip/hip_runtime.h>

#define NB 4
#define C 64
#define H 256
#define W 256
#define HW (H * W)
#define NH 10
#define KK 5
#define NBINS 1024
#define CHUNK 256
#define NCHUNK (HW / CHUNK)

// ---------------- per-batch sum of squares: grid 2048, part1[b*512+ch] ----------------
__global__ __launch_bounds__(256) void k_sumsq(const float* __restrict__ x,
                                               float* __restrict__ part1) {
    __shared__ float red[256];
    int u = blockIdx.x, t = threadIdx.x;
    int b = u >> 9, ch = u & 511;
    const float4* p = reinterpret_cast<const float4*>(x + (size_t)b * C * HW) + (size_t)ch * 2048;
    float s = 0.f;
    for (int i = t; i < 2048; i += 256) {
        float4 v = p[i];
        s += v.x * v.x + v.y * v.y + v.z * v.z + v.w * v.w;
    }
    red[t] = s;
    __syncthreads();
    for (int off = 128; off; off >>= 1) {
        if (t < off) red[t] += red[t + off];
        __syncthreads();
    }
    if (t == 0) part1[u] = red[0];
}

// ---------------- hash: 1024 threads, pixel-per-thread column walk ----------------
// t&255 = pixel within chunk, t>>8 = channel quarter (16 channels each).
// Fused redundant argmax; outputs dec, filtU, hist (bin-major).
__global__ __launch_bounds__(1024) void k_hash(const float* __restrict__ Xall,
                                               const float* __restrict__ part,
                                               int per_batch,
                                               const float* __restrict__ rvecs,
                                               const float* __restrict__ cwg,
                                               float* __restrict__ filtU,
                                               int* __restrict__ dec,
                                               int* __restrict__ hist) {
    __shared__ __align__(16) float smbuf[256 * 21];  // argmax red4[1024] (16KB) then reduce buf
    __shared__ int lhist[NBINS];
    int t = threadIdx.x;
    for (int i = t; i < NBINS; i += 1024) lhist[i] = 0;

    // redundant argmax over part[NB][per_batch]
    float4* red4 = reinterpret_cast<float4*>(smbuf);
    float4 ss = make_float4(0.f, 0.f, 0.f, 0.f);
    int q4 = per_batch >> 2;
    for (int i = t; i < q4; i += 1024) {
        float4 a = *reinterpret_cast<const float4*>(part + 0 * per_batch + i * 4);
        float4 b = *reinterpret_cast<const float4*>(part + 1 * per_batch + i * 4);
        float4 c = *reinterpret_cast<const float4*>(part + 2 * per_batch + i * 4);
        float4 d = *reinterpret_cast<const float4*>(part + 3 * per_batch + i * 4);
        ss.x += a.x + a.y + a.z + a.w;
        ss.y += b.x + b.y + b.z + b.w;
        ss.z += c.x + c.y + c.z + c.w;
        ss.w += d.x + d.y + d.z + d.w;
    }
    red4[t] = ss;
    __syncthreads();
    for (int off = 512; off; off >>= 1) {
        if (t < off) {
            red4[t].x += red4[t + off].x;
            red4[t].y += red4[t + off].y;
            red4[t].z += red4[t + off].z;
            red4[t].w += red4[t + off].w;
        }
        __syncthreads();
    }
    float4 nm = red4[0];
    __syncthreads();  // release smbuf
    float nv[NB] = {nm.x, nm.y, nm.z, nm.w};
    int best = 0;
    float m = nv[0];
#pragma unroll
    for (int i = 1; i < NB; i++)
        if (nv[i] > m) { m = nv[i]; best = i; }

    int pix = t & 255;
    int q = t >> 8;
    int p0 = blockIdx.x * CHUNK;
    const float* X = Xall + (size_t)best * C * HW + p0 + pix;

    float v[16];
#pragma unroll
    for (int k = 0; k < 16; k++) v[k] = X[(size_t)(q * 16 + k) * HW];

    float acc[NH], cacc[NH];
#pragma unroll
    for (int h = 0; h < NH; h++) { acc[h] = 0.f; cacc[h] = 0.f; }
#pragma unroll
    for (int k = 0; k < 16; k++) {
        int ci = q * 16 + k;  // wave-uniform -> scalar loads
#pragma unroll
        for (int h = 0; h < NH; h++) {
            acc[h] += v[k] * rvecs[h * C + ci];
            cacc[h] += v[k] * cwg[h * C + ci];
        }
    }

    // reduce quarters 1..3 into quarter 0 (padded stride 21 -> conflict-free)
    for (int qq = 1; qq < 4; qq++) {
        __syncthreads();
        if (q == qq) {
#pragma unroll
            for (int h = 0; h < NH; h++) {
                smbuf[pix * 21 + h] = acc[h];
                smbuf[pix * 21 + 10 + h] = cacc[h];
            }
        }
        __syncthreads();
        if (q == 0) {
#pragma unroll
            for (int h = 0; h < NH; h++) {
                acc[h] += smbuf[pix * 21 + h];
                cacc[h] += smbuf[pix * 21 + 10 + h];
            }
        }
    }

    if (q == 0) {
        int d = 0;
#pragma unroll
        for (int h = 0; h < NH; h++) d |= (acc[h] > 0.f) ? (1 << h) : 0;
        dec[p0 + pix] = d;
        atomicAdd(&lhist[d], 1);
        float sg[NH];
#pragma unroll
        for (int h = 0; h < NH; h++) sg[h] = 1.f / (1.f + expf(-cacc[h]));
        float* fu = filtU + (size_t)(p0 + pix) * 12;
        *reinterpret_cast<float4*>(fu + 0) = make_float4(sg[0], sg[1], sg[2], sg[3]);
        *reinterpret_cast<float4*>(fu + 4) = make_float4(sg[4], sg[5], sg[6], sg[7]);
        *reinterpret_cast<float4*>(fu + 8) = make_float4(sg[8], sg[9], 0.f, 0.f);
    }
    __syncthreads();
    for (int i = t; i < NBINS; i += 1024) hist[(size_t)i * NCHUNK + blockIdx.x] = lhist[i];
}

// ---------------- per-bin chunk scan: one bin per wave ----------------
__global__ __launch_bounds__(256) void k_scan(int* __restrict__ hist,
                                              int* __restrict__ bintot) {
    int t = threadIdx.x;
    int lane = t & 63;
    int b = blockIdx.x * 4 + (t >> 6);
    int4 v = *reinterpret_cast<int4*>(hist + (size_t)b * NCHUNK + lane * 4);
    int s0 = v.x, s1 = s0 + v.y, s2 = s1 + v.z, s3 = s2 + v.w;
    int s = s3;
#pragma unroll
    for (int off = 1; off < 64; off <<= 1) {
        int nbr = __shfl_up(s, off);
        if (lane >= off) s += nbr;
    }
    int excl = s - s3;
    int4 o;
    o.x = excl;
    o.y = excl + s0;
    o.z = excl + s1;
    o.w = excl + s2;
    *reinterpret_cast<int4*>(hist + (size_t)b * NCHUNK + lane * 4) = o;
    if (lane == 63) bintot[b] = s;
}

// ---------------- stable scatter with ballot-match rank ----------------
__global__ __launch_bounds__(256) void k_scatter(const int* __restrict__ dec,
                                                 const int* __restrict__ hist,
                                                 const int* __restrict__ bintot,
                                                 const float* __restrict__ filtU,
                                                 float* __restrict__ filt) {
    __shared__ int boffs[NBINS];
    __shared__ int wtot[4];
    __shared__ int lhw[4][NBINS];
    int t = threadIdx.x;
    int lane = t & 63;
    int w = t >> 6;
    for (int i = t; i < 4 * NBINS; i += 256) (&lhw[0][0])[i] = 0;

    int p0 = blockIdx.x * CHUNK;
    int k = dec[p0 + t];

    // exclusive scan of bintot -> boffs
    int4 v = *reinterpret_cast<const int4*>(bintot + t * 4);
    int s0 = v.x, s1 = s0 + v.y, s2 = s1 + v.z, s3 = s2 + v.w;
    int s = s3;
#pragma unroll
    for (int off = 1; off < 64; off <<= 1) {
        int nbr = __shfl_up(s, off);
        if (lane >= off) s += nbr;
    }
    int excl = s - s3;
    if (lane == 63) wtot[w] = s;
    __syncthreads();  // lhw zeros + wtot visible
    int wbase = 0;
#pragma unroll
    for (int i = 0; i < 4; i++) wbase += (i < w) ? wtot[i] : 0;
    boffs[t * 4 + 0] = wbase + excl;
    boffs[t * 4 + 1] = wbase + excl + s0;
    boffs[t * 4 + 2] = wbase + excl + s1;
    boffs[t * 4 + 3] = wbase + excl + s2;

    atomicAdd(&lhw[w][k], 1);
    // in-wave equal-key mask via 10 ballots
    unsigned long long msk = ~0ull;
#pragma unroll
    for (int b = 0; b < 10; b++) {
        int bit = (k >> b) & 1;
        unsigned long long bb = __ballot(bit);
        msk &= bit ? bb : ~bb;
    }
    int rin = __popcll(msk & ((1ull << lane) - 1ull));
    __syncthreads();  // boffs + lhw atomics visible

    int r = rin;
#pragma unroll
    for (int w2 = 0; w2 < 3; w2++) r += (w2 < w) ? lhw[w2][k] : 0;
    int dst = boffs[k] + hist[(size_t)k * NCHUNK + blockIdx.x] + r;

    const float4* fu = reinterpret_cast<const float4*>(filtU + (size_t)(p0 + t) * 12);
    float4 a = fu[0], b4 = fu[1], c4 = fu[2];
    float vv[10] = {a.x, a.y, a.z, a.w, b4.x, b4.y, b4.z, b4.w, c4.x, c4.y};
#pragma unroll
    for (int h = 0; h < NH; h++) filt[(size_t)h * HW + dst] = vv[h];
}

// ---------------- horizontal strip conv (float4) + part2 partials ----------------
__global__ __launch_bounds__(256) void k_convh(const float* __restrict__ X,
                                               const float* __restrict__ filt,
                                               float* __restrict__ out1,
                                               float* __restrict__ part2) {
    __shared__ float wred[4];
    int u = blockIdx.x, t = threadIdx.x;
    int rb = u & 63;
    int c = (u >> 6) & (C - 1);
    int n = u >> 12;
    int g = c >> 5;
    int x4 = (t & 63) * 4;
    int y = rb * 4 + (t >> 6);

    const float* src = X + (((size_t)n * C + c) * H + y) * W;
    float4 M = *reinterpret_cast<const float4*>(src + x4);
    float s0, s1, s6, s7;
    if (x4 > 0) {
        float4 L = *reinterpret_cast<const float4*>(src + x4 - 4);
        s0 = L.z; s1 = L.w;
    } else {
        s0 = M.z; s1 = M.y;
    }
    if (x4 < W - 4) {
        float4 R = *reinterpret_cast<const float4*>(src + x4 + 4);
        s6 = R.x; s7 = R.y;
    } else {
        s6 = M.z; s7 = M.y;
    }
    float s[8] = {s0, s1, M.x, M.y, M.z, M.w, s6, s7};

    const float* fb = filt + (size_t)g * KK * HW + (size_t)y * W + x4;
    float4 acc = make_float4(0.f, 0.f, 0.f, 0.f);
#pragma unroll
    for (int k = 0; k < KK; k++) {
        float4 f = *reinterpret_cast<const float4*>(fb + (size_t)k * HW);
        acc.x += s[k] * f.x;
        acc.y += s[k + 1] * f.y;
        acc.z += s[k + 2] * f.z;
        acc.w += s[k + 3] * f.w;
    }
    *reinterpret_cast<float4*>(out1 + (((size_t)n * C + c) * H + y) * W + x4) = acc;

    float ss = acc.x * acc.x + acc.y * acc.y + acc.z * acc.z + acc.w * acc.w;
#pragma unroll
    for (int off = 32; off; off >>= 1) ss += __shfl_down(ss, off);
    if ((t & 63) == 0) wred[t >> 6] = ss;
    __syncthreads();
    if (t == 0) part2[u] = wred[0] + wred[1] + wred[2] + wred[3];
}

// ---------------- vertical strip conv (float4 sliding window, TY=16) + affine ----------------
__global__ __launch_bounds__(256) void k_convv(const float* __restrict__ out1,
                                               const float* __restrict__ filt,
                                               const float* __restrict__ x,
                                               const float* __restrict__ gamma,
                                               const float* __restrict__ beta,
                                               float* __restrict__ out) {
    int u = blockIdx.x, t = threadIdx.x;
    int yc = u & 3;
    int c = (u >> 2) & (C - 1);
    int n = u >> 8;
    int g = c >> 5;
    int x4 = (t & 63) * 4;
    int ys = yc * 64 + (t >> 6) * 16;

    const float* plane = out1 + ((size_t)n * C + c) * HW;
    float4 win[KK];
#pragma unroll
    for (int i = 0; i < 4; i++) {
        int yy = ys - 2 + i;
        yy = yy < 0 ? -yy : yy;
        win[i] = *reinterpret_cast<const float4*>(plane + (size_t)yy * W + x4);
    }
    float gm = gamma[c], bt = beta[c];
    const float* fgb = filt + (size_t)g * KK * HW;
    for (int dy = 0; dy < 16; dy++) {
        int y = ys + dy;
        int yy = y + 2;
        yy = (yy >= H) ? (2 * H - 2 - yy) : yy;
        win[4] = *reinterpret_cast<const float4*>(plane + (size_t)yy * W + x4);
        const float* fb = fgb + (size_t)y * W + x4;
        float4 acc = make_float4(0.f, 0.f, 0.f, 0.f);
#pragma unroll
        for (int k = 0; k < KK; k++) {
            float4 f = *reinterpret_cast<const float4*>(fb + (size_t)k * HW);
            acc.x += win[k].x * f.x;
            acc.y += win[k].y * f.y;
            acc.z += win[k].z * f.z;
            acc.w += win[k].w * f.w;
        }
        size_t idx = (((size_t)n * C + c) * H + y) * W + x4;
        float4 xv = *reinterpret_cast<const float4*>(x + idx);
        float4 o;
        o.x = gm * acc.x + bt * xv.x;
        o.y = gm * acc.y + bt * xv.y;
        o.z = gm * acc.z + bt * xv.z;
        o.w = gm * acc.w + bt * xv.w;
        *reinterpret_cast<float4*>(out + idx) = o;
#pragma unroll
        for (int k = 0; k < 4; k++) win[k] = win[k + 1];
    }
}

extern "C" void kernel_launch(void* const* d_in, const int* in_sizes, int n_in,
                              void* d_out, int out_size, void* d_ws, size_t ws_size,
                              hipStream_t stream) {
    const float* x      = (const float*)d_in[0];
    const float* conv_h = (const float*)d_in[1];
    const float* conv_w = (const float*)d_in[2];
    const float* rv_h   = (const float*)d_in[3];
    const float* rv_w   = (const float*)d_in[4];
    const float* gamma  = (const float*)d_in[5];
    const float* beta   = (const float*)d_in[6];
    float* out = (float*)d_out;

    char* w = (char*)d_ws;
    size_t off = 0;
    float* out1   = (float*)(w + off); off += (size_t)NB * C * HW * 4;
    float* filtU  = (float*)(w + off); off += (size_t)HW * 12 * 4;
    float* filt   = (float*)(w + off); off += (size_t)NH * HW * 4;
    int*   dec    = (int*)  (w + off); off += (size_t)HW * 4;
    int*   hist   = (int*)  (w + off); off += (size_t)NBINS * NCHUNK * 4;
    int*   bintot = (int*)  (w + off); off += 4096;
    float* part1  = (float*)(w + off); off += (size_t)NB * 512 * 4;
    float* part2  = (float*)(w + off); off += (size_t)NB * 4096 * 4;

    // ---------------- pass 1: horizontal ----------------
    k_sumsq<<<2048, 256, 0, stream>>>(x, part1);
    k_hash<<<NCHUNK, 1024, 0, stream>>>(x, part1, 512, rv_h, conv_h, filtU, dec, hist);
    k_scan<<<NBINS / 4, 256, 0, stream>>>(hist, bintot);
    k_scatter<<<NCHUNK, 256, 0, stream>>>(dec, hist, bintot, filtU, filt);
    k_convh<<<NB * C * (H / 4), 256, 0, stream>>>(x, filt, out1, part2);

    // ---------------- pass 2: vertical + affine ----------------
    k_hash<<<NCHUNK, 1024, 0, stream>>>(out1, part2, 4096, rv_w, conv_w, filtU, dec, hist);
    k_scan<<<NBINS / 4, 256, 0, stream>>>(hist, bintot);
    k_scatter<<<NCHUNK, 256, 0, stream>>>(dec, hist, bintot, filtU, filt);
    k_convv<<<NB * C * 4, 256, 0, stream>>>(out1, filt, x, gamma, beta, out);
}

// Round 13
// 138.966 us; speedup vs baseline: 3.1001x; 1.0022x over previous
//
#include <hip/hip_runtime.h>

#define NB 4
#define C 64
#define H 256
#define W 256
#define HW (H * W)
#define NH 10
#define KK 5
#define NBINS 1024
#define CHUNK 256
#define NCHUNK (HW / CHUNK)

typedef float floatx4 __attribute__((ext_vector_type(4)));

// ---------------- per-batch sum of squares: grid 2048, part1[b*512+ch] ----------------
__global__ __launch_bounds__(256) void k_sumsq(const float* __restrict__ x,
                                               float* __restrict__ part1) {
    __shared__ float red[256];
    int u = blockIdx.x, t = threadIdx.x;
    int b = u >> 9, ch = u & 511;
    const float4* p = reinterpret_cast<const float4*>(x + (size_t)b * C * HW) + (size_t)ch * 2048;
    float s = 0.f;
    for (int i = t; i < 2048; i += 256) {
        float4 v = p[i];
        s += v.x * v.x + v.y * v.y + v.z * v.z + v.w * v.w;
    }
    red[t] = s;
    __syncthreads();
    for (int off = 128; off; off >>= 1) {
        if (t < off) red[t] += red[t + off];
        __syncthreads();
    }
    if (t == 0) part1[u] = red[0];
}

// ---------------- hash: 1024 threads, pixel-per-thread column walk ----------------
__global__ __launch_bounds__(1024) void k_hash(const float* __restrict__ Xall,
                                               const float* __restrict__ part,
                                               int per_batch,
                                               const float* __restrict__ rvecs,
                                               const float* __restrict__ cwg,
                                               float* __restrict__ filtU,
                                               int* __restrict__ dec,
                                               int* __restrict__ hist) {
    __shared__ __align__(16) float smbuf[256 * 21];
    __shared__ int lhist[NBINS];
    int t = threadIdx.x;
    for (int i = t; i < NBINS; i += 1024) lhist[i] = 0;

    float4* red4 = reinterpret_cast<float4*>(smbuf);
    float4 ss = make_float4(0.f, 0.f, 0.f, 0.f);
    int q4 = per_batch >> 2;
    for (int i = t; i < q4; i += 1024) {
        float4 a = *reinterpret_cast<const float4*>(part + 0 * per_batch + i * 4);
        float4 b = *reinterpret_cast<const float4*>(part + 1 * per_batch + i * 4);
        float4 c = *reinterpret_cast<const float4*>(part + 2 * per_batch + i * 4);
        float4 d = *reinterpret_cast<const float4*>(part + 3 * per_batch + i * 4);
        ss.x += a.x + a.y + a.z + a.w;
        ss.y += b.x + b.y + b.z + b.w;
        ss.z += c.x + c.y + c.z + c.w;
        ss.w += d.x + d.y + d.z + d.w;
    }
    red4[t] = ss;
    __syncthreads();
    for (int off = 512; off; off >>= 1) {
        if (t < off) {
            red4[t].x += red4[t + off].x;
            red4[t].y += red4[t + off].y;
            red4[t].z += red4[t + off].z;
            red4[t].w += red4[t + off].w;
        }
        __syncthreads();
    }
    float4 nm = red4[0];
    __syncthreads();
    float nv[NB] = {nm.x, nm.y, nm.z, nm.w};
    int best = 0;
    float m = nv[0];
#pragma unroll
    for (int i = 1; i < NB; i++)
        if (nv[i] > m) { m = nv[i]; best = i; }

    int pix = t & 255;
    int q = t >> 8;
    int p0 = blockIdx.x * CHUNK;
    const float* X = Xall + (size_t)best * C * HW + p0 + pix;

    float v[16];
#pragma unroll
    for (int k = 0; k < 16; k++) v[k] = X[(size_t)(q * 16 + k) * HW];

    float acc[NH], cacc[NH];
#pragma unroll
    for (int h = 0; h < NH; h++) { acc[h] = 0.f; cacc[h] = 0.f; }
#pragma unroll
    for (int k = 0; k < 16; k++) {
        int ci = q * 16 + k;
#pragma unroll
        for (int h = 0; h < NH; h++) {
            acc[h] += v[k] * rvecs[h * C + ci];
            cacc[h] += v[k] * cwg[h * C + ci];
        }
    }

    for (int qq = 1; qq < 4; qq++) {
        __syncthreads();
        if (q == qq) {
#pragma unroll
            for (int h = 0; h < NH; h++) {
                smbuf[pix * 21 + h] = acc[h];
                smbuf[pix * 21 + 10 + h] = cacc[h];
            }
        }
        __syncthreads();
        if (q == 0) {
#pragma unroll
            for (int h = 0; h < NH; h++) {
                acc[h] += smbuf[pix * 21 + h];
                cacc[h] += smbuf[pix * 21 + 10 + h];
            }
        }
    }

    if (q == 0) {
        int d = 0;
#pragma unroll
        for (int h = 0; h < NH; h++) d |= (acc[h] > 0.f) ? (1 << h) : 0;
        dec[p0 + pix] = d;
        atomicAdd(&lhist[d], 1);
        float sg[NH];
#pragma unroll
        for (int h = 0; h < NH; h++) sg[h] = 1.f / (1.f + expf(-cacc[h]));
        float* fu = filtU + (size_t)(p0 + pix) * 12;
        *reinterpret_cast<float4*>(fu + 0) = make_float4(sg[0], sg[1], sg[2], sg[3]);
        *reinterpret_cast<float4*>(fu + 4) = make_float4(sg[4], sg[5], sg[6], sg[7]);
        *reinterpret_cast<float4*>(fu + 8) = make_float4(sg[8], sg[9], 0.f, 0.f);
    }
    __syncthreads();
    for (int i = t; i < NBINS; i += 1024) hist[(size_t)i * NCHUNK + blockIdx.x] = lhist[i];
}

// ---------------- per-bin chunk scan: one bin per wave ----------------
__global__ __launch_bounds__(256) void k_scan(int* __restrict__ hist,
                                              int* __restrict__ bintot) {
    int t = threadIdx.x;
    int lane = t & 63;
    int b = blockIdx.x * 4 + (t >> 6);
    int4 v = *reinterpret_cast<int4*>(hist + (size_t)b * NCHUNK + lane * 4);
    int s0 = v.x, s1 = s0 + v.y, s2 = s1 + v.z, s3 = s2 + v.w;
    int s = s3;
#pragma unroll
    for (int off = 1; off < 64; off <<= 1) {
        int nbr = __shfl_up(s, off);
        if (lane >= off) s += nbr;
    }
    int excl = s - s3;
    int4 o;
    o.x = excl;
    o.y = excl + s0;
    o.z = excl + s1;
    o.w = excl + s2;
    *reinterpret_cast<int4*>(hist + (size_t)b * NCHUNK + lane * 4) = o;
    if (lane == 63) bintot[b] = s;
}

// ---------------- stable scatter with ballot-match rank ----------------
__global__ __launch_bounds__(256) void k_scatter(const int* __restrict__ dec,
                                                 const int* __restrict__ hist,
                                                 const int* __restrict__ bintot,
                                                 const float* __restrict__ filtU,
                                                 float* __restrict__ filt) {
    __shared__ int boffs[NBINS];
    __shared__ int wtot[4];
    __shared__ int lhw[4][NBINS];
    int t = threadIdx.x;
    int lane = t & 63;
    int w = t >> 6;
    for (int i = t; i < 4 * NBINS; i += 256) (&lhw[0][0])[i] = 0;

    int p0 = blockIdx.x * CHUNK;
    int k = dec[p0 + t];

    int4 v = *reinterpret_cast<const int4*>(bintot + t * 4);
    int s0 = v.x, s1 = s0 + v.y, s2 = s1 + v.z, s3 = s2 + v.w;
    int s = s3;
#pragma unroll
    for (int off = 1; off < 64; off <<= 1) {
        int nbr = __shfl_up(s, off);
        if (lane >= off) s += nbr;
    }
    int excl = s - s3;
    if (lane == 63) wtot[w] = s;
    __syncthreads();
    int wbase = 0;
#pragma unroll
    for (int i = 0; i < 4; i++) wbase += (i < w) ? wtot[i] : 0;
    boffs[t * 4 + 0] = wbase + excl;
    boffs[t * 4 + 1] = wbase + excl + s0;
    boffs[t * 4 + 2] = wbase + excl + s1;
    boffs[t * 4 + 3] = wbase + excl + s2;

    atomicAdd(&lhw[w][k], 1);
    unsigned long long msk = ~0ull;
#pragma unroll
    for (int b = 0; b < 10; b++) {
        int bit = (k >> b) & 1;
        unsigned long long bb = __ballot(bit);
        msk &= bit ? bb : ~bb;
    }
    int rin = __popcll(msk & ((1ull << lane) - 1ull));
    __syncthreads();

    int r = rin;
#pragma unroll
    for (int w2 = 0; w2 < 3; w2++) r += (w2 < w) ? lhw[w2][k] : 0;
    int dst = boffs[k] + hist[(size_t)k * NCHUNK + blockIdx.x] + r;

    const float4* fu = reinterpret_cast<const float4*>(filtU + (size_t)(p0 + t) * 12);
    float4 a = fu[0], b4 = fu[1], c4 = fu[2];
    float vv[10] = {a.x, a.y, a.z, a.w, b4.x, b4.y, b4.z, b4.w, c4.x, c4.y};
#pragma unroll
    for (int h = 0; h < NH; h++) filt[(size_t)h * HW + dst] = vv[h];
}

// ---------------- horizontal strip conv (float4) + part2 partials ----------------
__global__ __launch_bounds__(256) void k_convh(const float* __restrict__ X,
                                               const float* __restrict__ filt,
                                               float* __restrict__ out1,
                                               float* __restrict__ part2) {
    __shared__ float wred[4];
    int u = blockIdx.x, t = threadIdx.x;
    int rb = u & 63;
    int c = (u >> 6) & (C - 1);
    int n = u >> 12;
    int g = c >> 5;
    int x4 = (t & 63) * 4;
    int y = rb * 4 + (t >> 6);

    const float* src = X + (((size_t)n * C + c) * H + y) * W;
    float4 M = *reinterpret_cast<const float4*>(src + x4);
    float s0, s1, s6, s7;
    if (x4 > 0) {
        float4 L = *reinterpret_cast<const float4*>(src + x4 - 4);
        s0 = L.z; s1 = L.w;
    } else {
        s0 = M.z; s1 = M.y;
    }
    if (x4 < W - 4) {
        float4 R = *reinterpret_cast<const float4*>(src + x4 + 4);
        s6 = R.x; s7 = R.y;
    } else {
        s6 = M.z; s7 = M.y;
    }
    float s[8] = {s0, s1, M.x, M.y, M.z, M.w, s6, s7};

    const float* fb = filt + (size_t)g * KK * HW + (size_t)y * W + x4;
    float4 acc = make_float4(0.f, 0.f, 0.f, 0.f);
#pragma unroll
    for (int k = 0; k < KK; k++) {
        float4 f = *reinterpret_cast<const float4*>(fb + (size_t)k * HW);
        acc.x += s[k] * f.x;
        acc.y += s[k + 1] * f.y;
        acc.z += s[k + 2] * f.z;
        acc.w += s[k + 3] * f.w;
    }
    *reinterpret_cast<float4*>(out1 + (((size_t)n * C + c) * H + y) * W + x4) = acc;

    float ss = acc.x * acc.x + acc.y * acc.y + acc.z * acc.z + acc.w * acc.w;
#pragma unroll
    for (int off = 32; off; off >>= 1) ss += __shfl_down(ss, off);
    if ((t & 63) == 0) wred[t >> 6] = ss;
    __syncthreads();
    if (t == 0) part2[u] = wred[0] + wred[1] + wred[2] + wred[3];
}

// ---------------- vertical strip conv: 4-row groups with HBM prefetch + affine ----------------
__global__ __launch_bounds__(256, 4) void k_convv(const float* __restrict__ out1,
                                                  const float* __restrict__ filt,
                                                  const float* __restrict__ x,
                                                  const float* __restrict__ gamma,
                                                  const float* __restrict__ beta,
                                                  float* __restrict__ out) {
    int u = blockIdx.x, t = threadIdx.x;
    int yc = u & 3;
    int c = (u >> 2) & (C - 1);
    int n = u >> 8;
    int g = c >> 5;
    int x4 = (t & 63) * 4;
    int ys = yc * 64 + (t >> 6) * 16;

    const float* plane = out1 + ((size_t)n * C + c) * HW;
    const float* xpl = x + ((size_t)n * C + c) * HW;
    float* opl = out + ((size_t)n * C + c) * HW;
    float4 win[KK];
#pragma unroll
    for (int i = 0; i < 4; i++) {
        int yy = ys - 2 + i;
        yy = yy < 0 ? -yy : yy;
        win[i] = *reinterpret_cast<const float4*>(plane + (size_t)yy * W + x4);
    }
    float gm = gamma[c], bt = beta[c];
    const float* fgb = filt + (size_t)g * KK * HW;

#pragma unroll
    for (int g4 = 0; g4 < 4; g4++) {
        int base = ys + g4 * 4;
        // prefetch 4 plane rows (y+2 for y=base..base+3) and 4 x rows
        float4 pr[4], xv[4];
#pragma unroll
        for (int i = 0; i < 4; i++) {
            int yy = base + 2 + i;
            yy = (yy >= H) ? (2 * H - 2 - yy) : yy;
            pr[i] = *reinterpret_cast<const float4*>(plane + (size_t)yy * W + x4);
            xv[i] = *reinterpret_cast<const float4*>(xpl + (size_t)(base + i) * W + x4);
        }
#pragma unroll
        for (int i = 0; i < 4; i++) {
            int y = base + i;
            win[4] = pr[i];
            const float* fb = fgb + (size_t)y * W + x4;
            float4 acc = make_float4(0.f, 0.f, 0.f, 0.f);
#pragma unroll
            for (int k = 0; k < KK; k++) {
                float4 f = *reinterpret_cast<const float4*>(fb + (size_t)k * HW);
                acc.x += win[k].x * f.x;
                acc.y += win[k].y * f.y;
                acc.z += win[k].z * f.z;
                acc.w += win[k].w * f.w;
            }
            floatx4 o;
            o.x = gm * acc.x + bt * xv[i].x;
            o.y = gm * acc.y + bt * xv[i].y;
            o.z = gm * acc.z + bt * xv[i].z;
            o.w = gm * acc.w + bt * xv[i].w;
            __builtin_nontemporal_store(o, reinterpret_cast<floatx4*>(opl + (size_t)y * W + x4));
#pragma unroll
            for (int k = 0; k < 4; k++) win[k] = win[k + 1];
        }
    }
}

extern "C" void kernel_launch(void* const* d_in, const int* in_sizes, int n_in,
                              void* d_out, int out_size, void* d_ws, size_t ws_size,
                              hipStream_t stream) {
    const float* x      = (const float*)d_in[0];
    const float* conv_h = (const float*)d_in[1];
    const float* conv_w = (const float*)d_in[2];
    const float* rv_h   = (const float*)d_in[3];
    const float* rv_w   = (const float*)d_in[4];
    const float* gamma  = (const float*)d_in[5];
    const float* beta   = (const float*)d_in[6];
    float* out = (float*)d_out;

    char* w = (char*)d_ws;
    size_t off = 0;
    float* out1   = (float*)(w + off); off += (size_t)NB * C * HW * 4;
    float* filtU  = (float*)(w + off); off += (size_t)HW * 12 * 4;
    float* filt   = (float*)(w + off); off += (size_t)NH * HW * 4;
    int*   dec    = (int*)  (w + off); off += (size_t)HW * 4;
    int*   hist   = (int*)  (w + off); off += (size_t)NBINS * NCHUNK * 4;
    int*   bintot = (int*)  (w + off); off += 4096;
    float* part1  = (float*)(w + off); off += (size_t)NB * 512 * 4;
    float* part2  = (float*)(w + off); off += (size_t)NB * 4096 * 4;

    // ---------------- pass 1: horizontal ----------------
    k_sumsq<<<2048, 256, 0, stream>>>(x, part1);
    k_hash<<<NCHUNK, 1024, 0, stream>>>(x, part1, 512, rv_h, conv_h, filtU, dec, hist);
    k_scan<<<NBINS / 4, 256, 0, stream>>>(hist, bintot);
    k_scatter<<<NCHUNK, 256, 0, stream>>>(dec, hist, bintot, filtU, filt);
    k_convh<<<NB * C * (H / 4), 256, 0, stream>>>(x, filt, out1, part2);

    // ---------------- pass 2: vertical + affine ----------------
    k_hash<<<NCHUNK, 1024, 0, stream>>>(out1, part2, 4096, rv_w, conv_w, filtU, dec, hist);
    k_scan<<<NBINS / 4, 256, 0, stream>>>(hist, bintot);
    k_scatter<<<NCHUNK, 256, 0, stream>>>(dec, hist, bintot, filtU, filt);
    k_convv<<<NB * C * 4, 256, 0, stream>>>(out1, filt, x, gamma, beta, out);
}

// Round 14
// 137.425 us; speedup vs baseline: 3.1348x; 1.0112x over previous
//
#include <hip/hip_runtime.h>

#define NB 4
#define C 64
#define H 256
#define W 256
#define HW (H * W)
#define NH 10
#define KK 5
#define NBINS 1024
#define CHUNK 256
#define NCHUNK (HW / CHUNK)

typedef float floatx4 __attribute__((ext_vector_type(4)));

// ---------------- per-batch sum of squares: grid 2048, part1[b*512+ch] ----------------
__global__ __launch_bounds__(256) void k_sumsq(const float* __restrict__ x,
                                               float* __restrict__ part1) {
    __shared__ float red[256];
    int u = blockIdx.x, t = threadIdx.x;
    int b = u >> 9, ch = u & 511;
    const float4* p = reinterpret_cast<const float4*>(x + (size_t)b * C * HW) + (size_t)ch * 2048;
    float s = 0.f;
    for (int i = t; i < 2048; i += 256) {
        float4 v = p[i];
        s += v.x * v.x + v.y * v.y + v.z * v.z + v.w * v.w;
    }
    red[t] = s;
    __syncthreads();
    for (int off = 128; off; off >>= 1) {
        if (t < off) red[t] += red[t + off];
        __syncthreads();
    }
    if (t == 0) part1[u] = red[0];
}

// ---------------- hash: 1024 threads, pixel-per-thread column walk ----------------
__global__ __launch_bounds__(1024) void k_hash(const float* __restrict__ Xall,
                                               const float* __restrict__ part,
                                               int per_batch,
                                               const float* __restrict__ rvecs,
                                               const float* __restrict__ cwg,
                                               float* __restrict__ filtU,
                                               int* __restrict__ dec,
                                               int* __restrict__ hist) {
    __shared__ __align__(16) float smbuf[256 * 21];
    __shared__ int lhist[NBINS];
    int t = threadIdx.x;
    for (int i = t; i < NBINS; i += 1024) lhist[i] = 0;

    float4* red4 = reinterpret_cast<float4*>(smbuf);
    float4 ss = make_float4(0.f, 0.f, 0.f, 0.f);
    int q4 = per_batch >> 2;
    for (int i = t; i < q4; i += 1024) {
        float4 a = *reinterpret_cast<const float4*>(part + 0 * per_batch + i * 4);
        float4 b = *reinterpret_cast<const float4*>(part + 1 * per_batch + i * 4);
        float4 c = *reinterpret_cast<const float4*>(part + 2 * per_batch + i * 4);
        float4 d = *reinterpret_cast<const float4*>(part + 3 * per_batch + i * 4);
        ss.x += a.x + a.y + a.z + a.w;
        ss.y += b.x + b.y + b.z + b.w;
        ss.z += c.x + c.y + c.z + c.w;
        ss.w += d.x + d.y + d.z + d.w;
    }
    red4[t] = ss;
    __syncthreads();
    for (int off = 512; off; off >>= 1) {
        if (t < off) {
            red4[t].x += red4[t + off].x;
            red4[t].y += red4[t + off].y;
            red4[t].z += red4[t + off].z;
            red4[t].w += red4[t + off].w;
        }
        __syncthreads();
    }
    float4 nm = red4[0];
    __syncthreads();
    float nv[NB] = {nm.x, nm.y, nm.z, nm.w};
    int best = 0;
    float m = nv[0];
#pragma unroll
    for (int i = 1; i < NB; i++)
        if (nv[i] > m) { m = nv[i]; best = i; }

    int pix = t & 255;
    int q = t >> 8;
    int p0 = blockIdx.x * CHUNK;
    const float* X = Xall + (size_t)best * C * HW + p0 + pix;

    float v[16];
#pragma unroll
    for (int k = 0; k < 16; k++) v[k] = X[(size_t)(q * 16 + k) * HW];

    float acc[NH], cacc[NH];
#pragma unroll
    for (int h = 0; h < NH; h++) { acc[h] = 0.f; cacc[h] = 0.f; }
#pragma unroll
    for (int k = 0; k < 16; k++) {
        int ci = q * 16 + k;
#pragma unroll
        for (int h = 0; h < NH; h++) {
            acc[h] += v[k] * rvecs[h * C + ci];
            cacc[h] += v[k] * cwg[h * C + ci];
        }
    }

    for (int qq = 1; qq < 4; qq++) {
        __syncthreads();
        if (q == qq) {
#pragma unroll
            for (int h = 0; h < NH; h++) {
                smbuf[pix * 21 + h] = acc[h];
                smbuf[pix * 21 + 10 + h] = cacc[h];
            }
        }
        __syncthreads();
        if (q == 0) {
#pragma unroll
            for (int h = 0; h < NH; h++) {
                acc[h] += smbuf[pix * 21 + h];
                cacc[h] += smbuf[pix * 21 + 10 + h];
            }
        }
    }

    if (q == 0) {
        int d = 0;
#pragma unroll
        for (int h = 0; h < NH; h++) d |= (acc[h] > 0.f) ? (1 << h) : 0;
        dec[p0 + pix] = d;
        atomicAdd(&lhist[d], 1);
        float sg[NH];
#pragma unroll
        for (int h = 0; h < NH; h++) sg[h] = 1.f / (1.f + expf(-cacc[h]));
        float* fu = filtU + (size_t)(p0 + pix) * 12;
        *reinterpret_cast<float4*>(fu + 0) = make_float4(sg[0], sg[1], sg[2], sg[3]);
        *reinterpret_cast<float4*>(fu + 4) = make_float4(sg[4], sg[5], sg[6], sg[7]);
        *reinterpret_cast<float4*>(fu + 8) = make_float4(sg[8], sg[9], 0.f, 0.f);
    }
    __syncthreads();
    for (int i = t; i < NBINS; i += 1024) hist[(size_t)i * NCHUNK + blockIdx.x] = lhist[i];
}

// ---------------- per-bin chunk scan: one bin per wave ----------------
__global__ __launch_bounds__(256) void k_scan(int* __restrict__ hist,
                                              int* __restrict__ bintot) {
    int t = threadIdx.x;
    int lane = t & 63;
    int b = blockIdx.x * 4 + (t >> 6);
    int4 v = *reinterpret_cast<int4*>(hist + (size_t)b * NCHUNK + lane * 4);
    int s0 = v.x, s1 = s0 + v.y, s2 = s1 + v.z, s3 = s2 + v.w;
    int s = s3;
#pragma unroll
    for (int off = 1; off < 64; off <<= 1) {
        int nbr = __shfl_up(s, off);
        if (lane >= off) s += nbr;
    }
    int excl = s - s3;
    int4 o;
    o.x = excl;
    o.y = excl + s0;
    o.z = excl + s1;
    o.w = excl + s2;
    *reinterpret_cast<int4*>(hist + (size_t)b * NCHUNK + lane * 4) = o;
    if (lane == 63) bintot[b] = s;
}

// ---------------- stable scatter with ballot-match rank ----------------
__global__ __launch_bounds__(256) void k_scatter(const int* __restrict__ dec,
                                                 const int* __restrict__ hist,
                                                 const int* __restrict__ bintot,
                                                 const float* __restrict__ filtU,
                                                 float* __restrict__ filt) {
    __shared__ int boffs[NBINS];
    __shared__ int wtot[4];
    __shared__ int lhw[4][NBINS];
    int t = threadIdx.x;
    int lane = t & 63;
    int w = t >> 6;
    for (int i = t; i < 4 * NBINS; i += 256) (&lhw[0][0])[i] = 0;

    int p0 = blockIdx.x * CHUNK;
    int k = dec[p0 + t];

    int4 v = *reinterpret_cast<const int4*>(bintot + t * 4);
    int s0 = v.x, s1 = s0 + v.y, s2 = s1 + v.z, s3 = s2 + v.w;
    int s = s3;
#pragma unroll
    for (int off = 1; off < 64; off <<= 1) {
        int nbr = __shfl_up(s, off);
        if (lane >= off) s += nbr;
    }
    int excl = s - s3;
    if (lane == 63) wtot[w] = s;
    __syncthreads();
    int wbase = 0;
#pragma unroll
    for (int i = 0; i < 4; i++) wbase += (i < w) ? wtot[i] : 0;
    boffs[t * 4 + 0] = wbase + excl;
    boffs[t * 4 + 1] = wbase + excl + s0;
    boffs[t * 4 + 2] = wbase + excl + s1;
    boffs[t * 4 + 3] = wbase + excl + s2;

    atomicAdd(&lhw[w][k], 1);
    unsigned long long msk = ~0ull;
#pragma unroll
    for (int b = 0; b < 10; b++) {
        int bit = (k >> b) & 1;
        unsigned long long bb = __ballot(bit);
        msk &= bit ? bb : ~bb;
    }
    int rin = __popcll(msk & ((1ull << lane) - 1ull));
    __syncthreads();

    int r = rin;
#pragma unroll
    for (int w2 = 0; w2 < 3; w2++) r += (w2 < w) ? lhw[w2][k] : 0;
    int dst = boffs[k] + hist[(size_t)k * NCHUNK + blockIdx.x] + r;

    const float4* fu = reinterpret_cast<const float4*>(filtU + (size_t)(p0 + t) * 12);
    float4 a = fu[0], b4 = fu[1], c4 = fu[2];
    float vv[10] = {a.x, a.y, a.z, a.w, b4.x, b4.y, b4.z, b4.w, c4.x, c4.y};
#pragma unroll
    for (int h = 0; h < NH; h++) filt[(size_t)h * HW + dst] = vv[h];
}

// ---------------- horizontal strip conv (float4) + part2 partials ----------------
__global__ __launch_bounds__(256) void k_convh(const float* __restrict__ X,
                                               const float* __restrict__ filt,
                                               float* __restrict__ out1,
                                               float* __restrict__ part2) {
    __shared__ float wred[4];
    int u = blockIdx.x, t = threadIdx.x;
    int rb = u & 63;
    int c = (u >> 6) & (C - 1);
    int n = u >> 12;
    int g = c >> 5;
    int x4 = (t & 63) * 4;
    int y = rb * 4 + (t >> 6);

    const float* src = X + (((size_t)n * C + c) * H + y) * W;
    float4 M = *reinterpret_cast<const float4*>(src + x4);
    float s0, s1, s6, s7;
    if (x4 > 0) {
        float4 L = *reinterpret_cast<const float4*>(src + x4 - 4);
        s0 = L.z; s1 = L.w;
    } else {
        s0 = M.z; s1 = M.y;
    }
    if (x4 < W - 4) {
        float4 R = *reinterpret_cast<const float4*>(src + x4 + 4);
        s6 = R.x; s7 = R.y;
    } else {
        s6 = M.z; s7 = M.y;
    }
    float s[8] = {s0, s1, M.x, M.y, M.z, M.w, s6, s7};

    const float* fb = filt + (size_t)g * KK * HW + (size_t)y * W + x4;
    float4 acc = make_float4(0.f, 0.f, 0.f, 0.f);
#pragma unroll
    for (int k = 0; k < KK; k++) {
        float4 f = *reinterpret_cast<const float4*>(fb + (size_t)k * HW);
        acc.x += s[k] * f.x;
        acc.y += s[k + 1] * f.y;
        acc.z += s[k + 2] * f.z;
        acc.w += s[k + 3] * f.w;
    }
    *reinterpret_cast<float4*>(out1 + (((size_t)n * C + c) * H + y) * W + x4) = acc;

    float ss = acc.x * acc.x + acc.y * acc.y + acc.z * acc.z + acc.w * acc.w;
#pragma unroll
    for (int off = 32; off; off >>= 1) ss += __shfl_down(ss, off);
    if ((t & 63) == 0) wred[t >> 6] = ss;
    __syncthreads();
    if (t == 0) part2[u] = wred[0] + wred[1] + wred[2] + wred[3];
}

// ---------------- vertical strip conv: TY=8, grid 2048 (8 blocks/CU), prefetch ----------------
__global__ __launch_bounds__(256) void k_convv(const float* __restrict__ out1,
                                               const float* __restrict__ filt,
                                               const float* __restrict__ x,
                                               const float* __restrict__ gamma,
                                               const float* __restrict__ beta,
                                               float* __restrict__ out) {
    int u = blockIdx.x, t = threadIdx.x;
    int yc = u & 7;
    int c = (u >> 3) & (C - 1);
    int n = u >> 9;
    int g = c >> 5;
    int x4 = (t & 63) * 4;
    int ys = yc * 32 + (t >> 6) * 8;

    const float* plane = out1 + ((size_t)n * C + c) * HW;
    const float* xpl = x + ((size_t)n * C + c) * HW;
    float* opl = out + ((size_t)n * C + c) * HW;
    float4 win[KK];
#pragma unroll
    for (int i = 0; i < 4; i++) {
        int yy = ys - 2 + i;
        yy = yy < 0 ? -yy : yy;
        win[i] = *reinterpret_cast<const float4*>(plane + (size_t)yy * W + x4);
    }
    float gm = gamma[c], bt = beta[c];
    const float* fgb = filt + (size_t)g * KK * HW;

#pragma unroll
    for (int g4 = 0; g4 < 2; g4++) {
        int base = ys + g4 * 4;
        // prefetch 4 plane rows (y+2 for y=base..base+3) and 4 x rows
        float4 pr[4], xv[4];
#pragma unroll
        for (int i = 0; i < 4; i++) {
            int yy = base + 2 + i;
            yy = (yy >= H) ? (2 * H - 2 - yy) : yy;
            pr[i] = *reinterpret_cast<const float4*>(plane + (size_t)yy * W + x4);
            xv[i] = *reinterpret_cast<const float4*>(xpl + (size_t)(base + i) * W + x4);
        }
#pragma unroll
        for (int i = 0; i < 4; i++) {
            int y = base + i;
            win[4] = pr[i];
            const float* fb = fgb + (size_t)y * W + x4;
            float4 acc = make_float4(0.f, 0.f, 0.f, 0.f);
#pragma unroll
            for (int k = 0; k < KK; k++) {
                float4 f = *reinterpret_cast<const float4*>(fb + (size_t)k * HW);
                acc.x += win[k].x * f.x;
                acc.y += win[k].y * f.y;
                acc.z += win[k].z * f.z;
                acc.w += win[k].w * f.w;
            }
            floatx4 o;
            o.x = gm * acc.x + bt * xv[i].x;
            o.y = gm * acc.y + bt * xv[i].y;
            o.z = gm * acc.z + bt * xv[i].z;
            o.w = gm * acc.w + bt * xv[i].w;
            __builtin_nontemporal_store(o, reinterpret_cast<floatx4*>(opl + (size_t)y * W + x4));
#pragma unroll
            for (int k = 0; k < 4; k++) win[k] = win[k + 1];
        }
    }
}

extern "C" void kernel_launch(void* const* d_in, const int* in_sizes, int n_in,
                              void* d_out, int out_size, void* d_ws, size_t ws_size,
                              hipStream_t stream) {
    const float* x      = (const float*)d_in[0];
    const float* conv_h = (const float*)d_in[1];
    const float* conv_w = (const float*)d_in[2];
    const float* rv_h   = (const float*)d_in[3];
    const float* rv_w   = (const float*)d_in[4];
    const float* gamma  = (const float*)d_in[5];
    const float* beta   = (const float*)d_in[6];
    float* out = (float*)d_out;

    char* w = (char*)d_ws;
    size_t off = 0;
    float* out1   = (float*)(w + off); off += (size_t)NB * C * HW * 4;
    float* filtU  = (float*)(w + off); off += (size_t)HW * 12 * 4;
    float* filt   = (float*)(w + off); off += (size_t)NH * HW * 4;
    int*   dec    = (int*)  (w + off); off += (size_t)HW * 4;
    int*   hist   = (int*)  (w + off); off += (size_t)NBINS * NCHUNK * 4;
    int*   bintot = (int*)  (w + off); off += 4096;
    float* part1  = (float*)(w + off); off += (size_t)NB * 512 * 4;
    float* part2  = (float*)(w + off); off += (size_t)NB * 4096 * 4;

    // ---------------- pass 1: horizontal ----------------
    k_sumsq<<<2048, 256, 0, stream>>>(x, part1);
    k_hash<<<NCHUNK, 1024, 0, stream>>>(x, part1, 512, rv_h, conv_h, filtU, dec, hist);
    k_scan<<<NBINS / 4, 256, 0, stream>>>(hist, bintot);
    k_scatter<<<NCHUNK, 256, 0, stream>>>(dec, hist, bintot, filtU, filt);
    k_convh<<<NB * C * (H / 4), 256, 0, stream>>>(x, filt, out1, part2);

    // ---------------- pass 2: vertical + affine ----------------
    k_hash<<<NCHUNK, 1024, 0, stream>>>(out1, part2, 4096, rv_w, conv_w, filtU, dec, hist);
    k_scan<<<NBINS / 4, 256, 0, stream>>>(hist, bintot);
    k_scatter<<<NCHUNK, 256, 0, stream>>>(dec, hist, bintot, filtU, filt);
    k_convv<<<NB * C * 8, 256, 0, stream>>>(out1, filt, x, gamma, beta, out);
}